// Round 1
// baseline (356.551 us; speedup 1.0000x reference)
//
#include <hip/hip_runtime.h>
#include <hip/hip_bf16.h>
#include <math.h>

#define SDIM 4096
#define EMB 512
#define NH 8
#define HD 64
#define QBLK 64
#define KVB 32
#define NB 2

typedef __attribute__((ext_vector_type(4))) float f32x4;
typedef __attribute__((ext_vector_type(8))) short bf16x8;
typedef __attribute__((ext_vector_type(4))) short bf16x4;

__device__ __forceinline__ short f2bf(float f) {
    union { float f; unsigned int u; } v; v.f = f;
    unsigned int u = v.u;
    unsigned int r = (u + 0x7fffu + ((u >> 16) & 1u)) >> 16;
    return (short)r;
}

// ---------------------------------------------------------------------------
// Flash attention (causal), one block = one (b,h) x 64-row q-tile.
// 4 waves, each wave owns 16 q rows. KV staged in 32-row tiles.
// Swapped QK^T: mfma(K,Q) -> S^T with q = lane&15 (softmax reduce = 2 shfl_xor).
// ---------------------------------------------------------------------------
__global__ __launch_bounds__(256, 2) void attn_fwd(
    const float* __restrict__ Q, const float* __restrict__ K,
    const float* __restrict__ V, short* __restrict__ X)
{
    __shared__ short Klds[KVB][72];     // K tile [kv][d], padded (2-way max)
    __shared__ short VTlds[HD][40];     // V^T tile [d][kv], padded
    __shared__ short Plds[4][16][40];   // per-wave P [q][kv], padded

    const int nqt = SDIM / QBLK;
    int qt = blockIdx.x % nqt;
    int bh = blockIdx.x / nqt;
    int b = bh / NH, h = bh % NH;

    int tid  = threadIdx.x;
    int wave = tid >> 6, lane = tid & 63;
    int g = lane >> 4, ln = lane & 15;

    // Q fragments held in registers: Q[q=ln (+wave*16)][d = kb*32 + g*8 + j]
    int qrow = qt * QBLK + wave * 16 + ln;
    const float* qp = Q + ((size_t)(b * SDIM + qrow)) * EMB + h * HD;
    bf16x8 qfrag[2];
#pragma unroll
    for (int kb = 0; kb < 2; ++kb) {
        const float* p = qp + kb * 32 + g * 8;
        float4 a = *(const float4*)p;
        float4 c = *(const float4*)(p + 4);
        bf16x8 f;
        f[0]=f2bf(a.x); f[1]=f2bf(a.y); f[2]=f2bf(a.z); f[3]=f2bf(a.w);
        f[4]=f2bf(c.x); f[5]=f2bf(c.y); f[6]=f2bf(c.z); f[7]=f2bf(c.w);
        qfrag[kb] = f;
    }

    float m_run = -INFINITY, l_run = 0.f;
    f32x4 acc_o[4];
#pragma unroll
    for (int i = 0; i < 4; ++i) acc_o[i] = (f32x4){0.f, 0.f, 0.f, 0.f};

    const int q_g    = qt * QBLK + wave * 16 + ln;   // this lane's q row
    const int qmax_w = qt * QBLK + wave * 16 + 15;   // wave's max q row
    const int kend   = qt * QBLK + QBLK;

    const int srow = tid >> 3;        // 0..31
    const int scol = (tid & 7) * 8;   // 0..56

    for (int k0 = 0; k0 < kend; k0 += KVB) {
        // ---- stage K tile and V^T tile (f32 -> bf16) ----
        {
            const float* kp = K + ((size_t)(b * SDIM + k0 + srow)) * EMB + h * HD + scol;
            float4 a = *(const float4*)kp;
            float4 c = *(const float4*)(kp + 4);
            bf16x8 f;
            f[0]=f2bf(a.x); f[1]=f2bf(a.y); f[2]=f2bf(a.z); f[3]=f2bf(a.w);
            f[4]=f2bf(c.x); f[5]=f2bf(c.y); f[6]=f2bf(c.z); f[7]=f2bf(c.w);
            *(bf16x8*)&Klds[srow][scol] = f;

            const float* vp = V + ((size_t)(b * SDIM + k0 + srow)) * EMB + h * HD + scol;
            float4 va = *(const float4*)vp;
            float4 vc = *(const float4*)(vp + 4);
            VTlds[scol + 0][srow] = f2bf(va.x);
            VTlds[scol + 1][srow] = f2bf(va.y);
            VTlds[scol + 2][srow] = f2bf(va.z);
            VTlds[scol + 3][srow] = f2bf(va.w);
            VTlds[scol + 4][srow] = f2bf(vc.x);
            VTlds[scol + 5][srow] = f2bf(vc.y);
            VTlds[scol + 6][srow] = f2bf(vc.z);
            VTlds[scol + 7][srow] = f2bf(vc.w);
        }
        __syncthreads();

        if (k0 <= qmax_w) {   // wave-uniform: skip fully-masked tiles
            float sv[8];
#pragma unroll
            for (int t2 = 0; t2 < 2; ++t2) {
                int kvr = t2 * 16 + ln;
                bf16x8 kf0 = *(bf16x8*)&Klds[kvr][g * 8];
                bf16x8 kf1 = *(bf16x8*)&Klds[kvr][32 + g * 8];
                f32x4 acc = (f32x4){0.f, 0.f, 0.f, 0.f};
                acc = __builtin_amdgcn_mfma_f32_16x16x32_bf16(kf0, qfrag[0], acc, 0, 0, 0);
                acc = __builtin_amdgcn_mfma_f32_16x16x32_bf16(kf1, qfrag[1], acc, 0, 0, 0);
#pragma unroll
                for (int r = 0; r < 4; ++r) {
                    int kv = k0 + t2 * 16 + g * 4 + r;     // C/D row = kv (m89 layout)
                    float s = acc[r] * 0.125f;
                    sv[t2 * 4 + r] = (kv > q_g) ? -INFINITY : s;
                }
            }
            // online softmax; q is lane-local (= ln), reduce over 4-lane group
            float mt = sv[0];
#pragma unroll
            for (int i = 1; i < 8; ++i) mt = fmaxf(mt, sv[i]);
            mt = fmaxf(mt, __shfl_xor(mt, 16, 64));
            mt = fmaxf(mt, __shfl_xor(mt, 32, 64));
            float m_new = fmaxf(m_run, mt);
            float rescale = expf(m_run - m_new);   // exp(-inf - finite) = 0 on first step
            float psum = 0.f;
            short pb[8];
#pragma unroll
            for (int i = 0; i < 8; ++i) {
                float p = expf(sv[i] - m_new);
                psum += p;
                pb[i] = f2bf(p);
            }
            psum += __shfl_xor(psum, 16, 64);
            psum += __shfl_xor(psum, 32, 64);
            l_run = l_run * rescale + psum;
            m_run = m_new;

            // rescale O rows (O row index = g*4+r, factor lives on lane q)
            float fr[4];
#pragma unroll
            for (int r = 0; r < 4; ++r) fr[r] = __shfl(rescale, g * 4 + r, 64);
#pragma unroll
            for (int dt = 0; dt < 4; ++dt)
#pragma unroll
                for (int r = 0; r < 4; ++r) acc_o[dt][r] *= fr[r];

            // P -> LDS in A-operand layout: Plds[w][q][kv]
            *(bf16x4*)&Plds[wave][ln][g * 4]      = (bf16x4){pb[0], pb[1], pb[2], pb[3]};
            *(bf16x4*)&Plds[wave][ln][16 + g * 4] = (bf16x4){pb[4], pb[5], pb[6], pb[7]};
            asm volatile("s_waitcnt lgkmcnt(0)" ::: "memory");
            __builtin_amdgcn_sched_barrier(0);

            // PV: O[q][d] += P[q][kv] * V[kv][d]
            bf16x8 pf = *(bf16x8*)&Plds[wave][ln][g * 8];
#pragma unroll
            for (int dt = 0; dt < 4; ++dt) {
                bf16x8 vf = *(bf16x8*)&VTlds[dt * 16 + ln][g * 8];
                acc_o[dt] = __builtin_amdgcn_mfma_f32_16x16x32_bf16(pf, vf, acc_o[dt], 0, 0, 0);
            }
        }
        __syncthreads();
    }

    // epilogue: O / l, write bf16 to workspace X[b*S+q][h*64+d]
    float linv[4];
#pragma unroll
    for (int r = 0; r < 4; ++r) {
        float lr = __shfl(l_run, g * 4 + r, 64);
        linv[r] = 1.f / lr;
    }
#pragma unroll
    for (int dt = 0; dt < 4; ++dt)
#pragma unroll
        for (int r = 0; r < 4; ++r) {
            int qr2 = qt * QBLK + wave * 16 + g * 4 + r;
            X[((size_t)(b * SDIM + qr2)) * EMB + h * HD + dt * 16 + ln] =
                f2bf(acc_o[dt][r] * linv[r]);
        }
}

// ---------------------------------------------------------------------------
// Output projection: out[i][j] = sum_e X[i][e] * Wo[j][e] + bo[j]
// 64x64 tile per block, BK=32, 4 waves x (16 rows x 64 cols)
// ---------------------------------------------------------------------------
__global__ __launch_bounds__(256, 2) void proj_gemm(
    const short* __restrict__ X, const float* __restrict__ Wo,
    const float* __restrict__ bo, float* __restrict__ out)
{
    __shared__ short Alds[64][40];
    __shared__ short Blds[64][40];

    int bj = blockIdx.x & 7;          // EMB/64 = 8 col tiles
    int bi = blockIdx.x >> 3;
    int i0 = bi * 64, j0 = bj * 64;

    int tid  = threadIdx.x;
    int wave = tid >> 6, lane = tid & 63;
    int g = lane >> 4, ln = lane & 15;
    int srow = tid >> 2, scol = (tid & 3) * 8;

    f32x4 acc[4];
#pragma unroll
    for (int i = 0; i < 4; ++i) acc[i] = (f32x4){0.f, 0.f, 0.f, 0.f};

    for (int e0 = 0; e0 < EMB; e0 += 32) {
        bf16x8 xa = *(const bf16x8*)&X[(size_t)(i0 + srow) * EMB + e0 + scol];
        *(bf16x8*)&Alds[srow][scol] = xa;

        const float* wp = Wo + (size_t)(j0 + srow) * EMB + e0 + scol;
        float4 a = *(const float4*)wp;
        float4 c = *(const float4*)(wp + 4);
        bf16x8 f;
        f[0]=f2bf(a.x); f[1]=f2bf(a.y); f[2]=f2bf(a.z); f[3]=f2bf(a.w);
        f[4]=f2bf(c.x); f[5]=f2bf(c.y); f[6]=f2bf(c.z); f[7]=f2bf(c.w);
        *(bf16x8*)&Blds[srow][scol] = f;
        __syncthreads();

        bf16x8 af = *(bf16x8*)&Alds[wave * 16 + ln][g * 8];
#pragma unroll
        for (int nt = 0; nt < 4; ++nt) {
            bf16x8 bf = *(bf16x8*)&Blds[nt * 16 + ln][g * 8];
            acc[nt] = __builtin_amdgcn_mfma_f32_16x16x32_bf16(af, bf, acc[nt], 0, 0, 0);
        }
        __syncthreads();
    }

#pragma unroll
    for (int nt = 0; nt < 4; ++nt)
#pragma unroll
        for (int r = 0; r < 4; ++r) {
            int row = i0 + wave * 16 + g * 4 + r;
            int col = j0 + nt * 16 + ln;
            out[(size_t)row * EMB + col] = acc[nt][r] + bo[col];
        }
}

extern "C" void kernel_launch(void* const* d_in, const int* in_sizes, int n_in,
                              void* d_out, int out_size, void* d_ws, size_t ws_size,
                              hipStream_t stream) {
    const float* Q  = (const float*)d_in[0];
    const float* K  = (const float*)d_in[1];
    const float* V  = (const float*)d_in[2];
    const float* Wo = (const float*)d_in[3];
    const float* bo = (const float*)d_in[4];
    // d_in[5] = mask (always 1 -> causal, per reference)
    short* X   = (short*)d_ws;                 // bf16 attn output, [B*S][EMB] = 8 MB
    float* out = (float*)d_out;

    attn_fwd<<<dim3(NB * NH * (SDIM / QBLK)), 256, 0, stream>>>(Q, K, V, X);
    proj_gemm<<<dim3((NB * SDIM / 64) * (EMB / 64)), 256, 0, stream>>>(X, Wo, bo, out);
}

// Round 2
// 171.590 us; speedup vs baseline: 2.0779x; 2.0779x over previous
//
#include <hip/hip_runtime.h>
#include <hip/hip_bf16.h>
#include <math.h>

#define SDIM 4096
#define EMB 512
#define NH 8
#define HD 64
#define QBLK 128            // per block: 4 waves x 32 q-rows
#define KVB 64
#define NB 2
#define NQT (SDIM / QBLK)   // 32

typedef __attribute__((ext_vector_type(4)))  float f32x4;
typedef __attribute__((ext_vector_type(16))) float f32x16;
typedef __attribute__((ext_vector_type(8)))  short bf16x8;
typedef __attribute__((ext_vector_type(4)))  unsigned u32x4;

#define SC  0.18033688011112042f   // log2(e) / sqrt(64)
#define THR 8.0f                   // defer-max threshold, log2 units

__device__ __forceinline__ unsigned cvt_pk(float lo, float hi) {
    unsigned r;
    asm("v_cvt_pk_bf16_f32 %0, %1, %2" : "=v"(r) : "v"(lo), "v"(hi));
    return r;
}
__device__ __forceinline__ void pl32swap(unsigned &a, unsigned &b) {
    asm("v_permlane32_swap_b32 %0, %1" : "+v"(a), "+v"(b));
}

// ---------------------------------------------------------------------------
// Flash attention (causal). Block = (b,h) x 128 q-rows; 4 waves x 32 q each.
// KV tiles of 64. mfma_f32_32x32x16_bf16, swapped QK^T (q lane-local),
// in-register softmax + T12 cvt_pk/permlane32_swap P-repack, T13 defer-max.
// K/V^T LDS tiles XOR-swizzled (T2).
// ---------------------------------------------------------------------------
__global__ __launch_bounds__(256) void attn_fwd(
    const float* __restrict__ Q, const float* __restrict__ K,
    const float* __restrict__ V, short* __restrict__ X)
{
    __shared__ short Kl[KVB * HD];   // [kv][d], rows 128B, byte ^ ((kv&7)<<4)
    __shared__ short Vt[HD * KVB];   // [d][kv], rows 128B, byte ^ ((d&7)<<4)

    int qt = (NQT - 1) - (blockIdx.x % NQT);   // heavy (late) q-tiles first
    int bh = blockIdx.x / NQT;
    int b = bh / NH, h = bh % NH;

    int tid  = threadIdx.x;
    int wave = tid >> 6, lane = tid & 63;
    int ln = lane & 31, hi = lane >> 5;
    int swz = 8 * (ln & 7);          // short-index XOR for row==ln rows
    int shbase = 36 * hi;            // (lane&32) + 4*hi  : shfl base for reg->q

    const int qbase = qt * QBLK + wave * 32;
    const int q_g   = qbase + ln;
    const int kend  = qt * QBLK + QBLK;

    // ---- Q fragments in registers: qf[s] elem j = Q[q_g][16s + 8hi + j] ----
    bf16x8 qf[4];
    {
        const float* qp = Q + ((size_t)(b * SDIM + q_g)) * EMB + h * HD + 8 * hi;
#pragma unroll
        for (int s = 0; s < 4; ++s) {
            f32x4 a = *(const f32x4*)(qp + 16 * s);
            f32x4 c = *(const f32x4*)(qp + 16 * s + 4);
            u32x4 w = { cvt_pk(a[0], a[1]), cvt_pk(a[2], a[3]),
                        cvt_pk(c[0], c[1]), cvt_pk(c[2], c[3]) };
            qf[s] = (bf16x8)w;
        }
    }

    float m2 = -1e30f, l_run = 0.f;
    f32x16 accO0 = {0.f,0.f,0.f,0.f,0.f,0.f,0.f,0.f,0.f,0.f,0.f,0.f,0.f,0.f,0.f,0.f};
    f32x16 accO1 = {0.f,0.f,0.f,0.f,0.f,0.f,0.f,0.f,0.f,0.f,0.f,0.f,0.f,0.f,0.f,0.f};

    // staging maps
    const int kr = tid >> 2, kc = (tid & 3) * 16;   // K: row kr, 16 d-cols
    const int vp = tid & 31, vdb = (tid >> 5) * 8;  // V: kv pair (2vp,2vp+1), 8 d

    for (int k0 = 0; k0 < kend; k0 += KVB) {
        // ---- stage K tile (f32 -> bf16, swizzled) ----
        {
            const float* kp = K + ((size_t)(b * SDIM + k0 + kr)) * EMB + h * HD + kc;
            f32x4 a0 = *(const f32x4*)(kp + 0);
            f32x4 a1 = *(const f32x4*)(kp + 4);
            f32x4 a2 = *(const f32x4*)(kp + 8);
            f32x4 a3 = *(const f32x4*)(kp + 12);
            int rs = 8 * (kr & 7);
            u32x4 w0 = { cvt_pk(a0[0],a0[1]), cvt_pk(a0[2],a0[3]),
                         cvt_pk(a1[0],a1[1]), cvt_pk(a1[2],a1[3]) };
            u32x4 w1 = { cvt_pk(a2[0],a2[1]), cvt_pk(a2[2],a2[3]),
                         cvt_pk(a3[0],a3[1]), cvt_pk(a3[2],a3[3]) };
            *(u32x4*)&Kl[kr * HD + ((kc + 0) ^ rs)] = w0;
            *(u32x4*)&Kl[kr * HD + ((kc + 8) ^ rs)] = w1;
        }
        // ---- stage V^T tile (kv-pair u32 writes, 2-way max conflicts) ----
        {
            const float* v0p = V + ((size_t)(b * SDIM + k0 + 2 * vp)) * EMB + h * HD + vdb;
            const float* v1p = v0p + EMB;
            f32x4 a0 = *(const f32x4*)(v0p);
            f32x4 a1 = *(const f32x4*)(v0p + 4);
            f32x4 b0 = *(const f32x4*)(v1p);
            f32x4 b1 = *(const f32x4*)(v1p + 4);
            unsigned* vt32 = (unsigned*)Vt;
#pragma unroll
            for (int i = 0; i < 4; ++i) {
                int d = vdb + i;
                vt32[d * 32 + (vp ^ (4 * (d & 7)))] = cvt_pk(a0[i], b0[i]);
            }
#pragma unroll
            for (int i = 0; i < 4; ++i) {
                int d = vdb + 4 + i;
                vt32[d * 32 + (vp ^ (4 * (d & 7)))] = cvt_pk(a1[i], b1[i]);
            }
        }
        __syncthreads();

        if (k0 <= qbase + 31) {   // wave-uniform: skip fully-masked tiles
            // ---- QK^T: S^T[kv][q], q = ln, kv on regs = crow(r,hi) ----
            float p0[16], p1[16];
#pragma unroll
            for (int t = 0; t < 2; ++t) {
                f32x16 acc = {0.f,0.f,0.f,0.f,0.f,0.f,0.f,0.f,
                              0.f,0.f,0.f,0.f,0.f,0.f,0.f,0.f};
#pragma unroll
                for (int s = 0; s < 4; ++s) {
                    bf16x8 kf = *(bf16x8*)&Kl[(32*t + ln) * HD + ((16*s + 8*hi) ^ swz)];
                    acc = __builtin_amdgcn_mfma_f32_32x32x16_bf16(kf, qf[s], acc, 0, 0, 0);
                }
                float* pt = t ? p1 : p0;
                if (k0 + 32*t + 31 > qbase) {        // diagonal-crossing: mask
#pragma unroll
                    for (int r = 0; r < 16; ++r) {
                        int kv = k0 + 32*t + (r & 3) + 8*(r >> 2) + 4*hi;
                        pt[r] = (kv > q_g) ? -INFINITY : acc[r] * SC;
                    }
                } else {
#pragma unroll
                    for (int r = 0; r < 16; ++r) pt[r] = acc[r] * SC;
                }
            }

            // ---- online softmax (log2 domain), q lane-local ----
            float mt = fmaxf(p0[0], p1[0]);
#pragma unroll
            for (int r = 1; r < 16; ++r) mt = fmaxf(mt, fmaxf(p0[r], p1[r]));
            mt = fmaxf(mt, __shfl_xor(mt, 32, 64));

            if (!__all(mt <= m2 + THR)) {            // T13 defer-max
                float m_new = fmaxf(m2, mt);
                float fac = __builtin_amdgcn_exp2f(m2 - m_new);
                m2 = m_new;
                l_run *= fac;
#pragma unroll
                for (int r = 0; r < 16; ++r) {
                    float fr = __shfl(fac, shbase + ((r & 3) + 8*(r >> 2)), 64);
                    accO0[r] *= fr;
                    accO1[r] *= fr;
                }
            }
            float psum = 0.f;
#pragma unroll
            for (int r = 0; r < 16; ++r) { p0[r] = __builtin_amdgcn_exp2f(p0[r] - m2); psum += p0[r]; }
#pragma unroll
            for (int r = 0; r < 16; ++r) { p1[r] = __builtin_amdgcn_exp2f(p1[r] - m2); psum += p1[r]; }
            psum += __shfl_xor(psum, 32, 64);
            l_run += psum;

            // ---- T12 repack P -> A-frags + PV ----
#pragma unroll
            for (int s = 0; s < 4; ++s) {
                const float* pt = (s >= 2) ? p1 : p0;
                const int u8 = (s & 1) * 8;
                unsigned w0 = cvt_pk(pt[u8 + 0], pt[u8 + 1]);
                unsigned w2 = cvt_pk(pt[u8 + 4], pt[u8 + 5]);
                pl32swap(w0, w2);
                unsigned w1 = cvt_pk(pt[u8 + 2], pt[u8 + 3]);
                unsigned w3 = cvt_pk(pt[u8 + 6], pt[u8 + 7]);
                pl32swap(w1, w3);
                u32x4 pw = { w0, w1, w2, w3 };
                bf16x8 pa = (bf16x8)pw;
                bf16x8 v0f = *(bf16x8*)&Vt[(ln)      * KVB + ((16*s + 8*hi) ^ swz)];
                bf16x8 v1f = *(bf16x8*)&Vt[(32 + ln) * KVB + ((16*s + 8*hi) ^ swz)];
                accO0 = __builtin_amdgcn_mfma_f32_32x32x16_bf16(pa, v0f, accO0, 0, 0, 0);
                accO1 = __builtin_amdgcn_mfma_f32_32x32x16_bf16(pa, v1f, accO1, 0, 0, 0);
            }
        }
        __syncthreads();
    }

    // ---- epilogue: O / l, write bf16 to X[token][h*64+d] ----
    float il = 1.f / l_run;
#pragma unroll
    for (int r = 0; r < 16; ++r) {
        float ir = __shfl(il, shbase + ((r & 3) + 8*(r >> 2)), 64);
        int q = qbase + (r & 3) + 8*(r >> 2) + 4*hi;
        size_t base = ((size_t)(b * SDIM + q)) * EMB + h * HD;
        X[base + ln]      = (short)cvt_pk(accO0[r] * ir, 0.f);
        X[base + 32 + ln] = (short)cvt_pk(accO1[r] * ir, 0.f);
    }
}

// ---------------------------------------------------------------------------
// Output projection: out[i][j] = sum_e X[i][e] * Wo[j][e] + bo[j]
// ---------------------------------------------------------------------------
__global__ __launch_bounds__(256, 2) void proj_gemm(
    const short* __restrict__ X, const float* __restrict__ Wo,
    const float* __restrict__ bo, float* __restrict__ out)
{
    __shared__ short Alds[64][40];
    __shared__ short Blds[64][40];

    int bj = blockIdx.x & 7;
    int bi = blockIdx.x >> 3;
    int i0 = bi * 64, j0 = bj * 64;

    int tid  = threadIdx.x;
    int wave = tid >> 6, lane = tid & 63;
    int g = lane >> 4, ln = lane & 15;
    int srow = tid >> 2, scol = (tid & 3) * 8;

    f32x4 acc[4];
#pragma unroll
    for (int i = 0; i < 4; ++i) acc[i] = (f32x4){0.f, 0.f, 0.f, 0.f};

    for (int e0 = 0; e0 < EMB; e0 += 32) {
        bf16x8 xa = *(const bf16x8*)&X[(size_t)(i0 + srow) * EMB + e0 + scol];
        *(bf16x8*)&Alds[srow][scol] = xa;

        const float* wp = Wo + (size_t)(j0 + srow) * EMB + e0 + scol;
        f32x4 a = *(const f32x4*)wp;
        f32x4 c = *(const f32x4*)(wp + 4);
        u32x4 w = { cvt_pk(a[0], a[1]), cvt_pk(a[2], a[3]),
                    cvt_pk(c[0], c[1]), cvt_pk(c[2], c[3]) };
        *(u32x4*)&Blds[srow][scol] = w;
        __syncthreads();

        bf16x8 af = *(bf16x8*)&Alds[wave * 16 + ln][g * 8];
#pragma unroll
        for (int nt = 0; nt < 4; ++nt) {
            bf16x8 bf = *(bf16x8*)&Blds[nt * 16 + ln][g * 8];
            acc[nt] = __builtin_amdgcn_mfma_f32_16x16x32_bf16(af, bf, acc[nt], 0, 0, 0);
        }
        __syncthreads();
    }

#pragma unroll
    for (int nt = 0; nt < 4; ++nt)
#pragma unroll
        for (int r = 0; r < 4; ++r) {
            int row = i0 + wave * 16 + g * 4 + r;
            int col = j0 + nt * 16 + ln;
            out[(size_t)row * EMB + col] = acc[nt][r] + bo[col];
        }
}

extern "C" void kernel_launch(void* const* d_in, const int* in_sizes, int n_in,
                              void* d_out, int out_size, void* d_ws, size_t ws_size,
                              hipStream_t stream) {
    const float* Q  = (const float*)d_in[0];
    const float* K  = (const float*)d_in[1];
    const float* V  = (const float*)d_in[2];
    const float* Wo = (const float*)d_in[3];
    const float* bo = (const float*)d_in[4];
    short* X   = (short*)d_ws;                 // bf16 attn output [B*S][EMB] = 16 MB
    float* out = (float*)d_out;

    attn_fwd<<<dim3(NB * NH * NQT), 256, 0, stream>>>(Q, K, V, X);
    proj_gemm<<<dim3((NB * SDIM / 64) * (EMB / 64)), 256, 0, stream>>>(X, Wo, bo, out);
}

// Round 3
// 126.638 us; speedup vs baseline: 2.8155x; 1.3550x over previous
//
#include <hip/hip_runtime.h>
#include <hip/hip_bf16.h>
#include <math.h>

#define SDIM 4096
#define EMB 512
#define NH 8
#define HD 64
#define QBLK 128            // per q-tile: 4 waves x 32 q-rows
#define KVB 64
#define NB 2
#define NQT (SDIM / QBLK)   // 32
#define NPAIR (NQT / 2)     // 16

typedef __attribute__((ext_vector_type(4)))  float f32x4;
typedef __attribute__((ext_vector_type(16))) float f32x16;
typedef __attribute__((ext_vector_type(8)))  short bf16x8;
typedef __attribute__((ext_vector_type(4)))  unsigned u32x4;

#define SC  0.18033688011112042f   // log2(e) / sqrt(64)
#define THR 8.0f                   // defer-max threshold, log2 units

__device__ __forceinline__ unsigned cvt_pk(float lo, float hi) {
    unsigned r;
    asm("v_cvt_pk_bf16_f32 %0, %1, %2" : "=v"(r) : "v"(lo), "v"(hi));
    return r;
}
__device__ __forceinline__ void pl32swap(unsigned &a, unsigned &b) {
    asm("v_permlane32_swap_b32 %0, %1" : "+v"(a), "+v"(b));
}

// ---------------------------------------------------------------------------
// Flash attention (causal). Block = (b,h) x q-tile PAIR (31-p, p), processed
// sequentially -> every block does exactly 66 KV-tile iterations (balanced).
// 4 waves x 32 q-rows. mfma_f32_32x32x16_bf16, swapped QK^T (q lane-local),
// T12 cvt_pk/permlane32_swap P-repack, T13 defer-max, T14 async-STAGE split,
// double-buffered LDS (1 barrier/iter), T2 XOR-swizzled K/V^T tiles.
// ---------------------------------------------------------------------------
__global__ __launch_bounds__(256) void attn_fwd(
    const float* __restrict__ Q, const float* __restrict__ K,
    const float* __restrict__ V, short* __restrict__ X)
{
    __shared__ short Kl[2][KVB * HD];   // [kv][d], byte ^ ((kv&7)<<4)
    __shared__ short Vt[2][HD * KVB];   // [d][kv], byte ^ ((d&7)<<4)

    int pair = blockIdx.x % NPAIR;
    int bh   = blockIdx.x / NPAIR;
    int b = bh / NH, h = bh % NH;

    int tid  = threadIdx.x;
    int wave = tid >> 6, lane = tid & 63;
    int ln = lane & 31, hi = lane >> 5;
    int swz = 8 * (ln & 7);
    int shbase = 36 * hi;               // (lane&32) + 4*hi

    // staging maps (per thread)
    const int kr = tid >> 2, kc = (tid & 3) * 16;   // K: row kr, 16 d
    const int vp = tid & 31, vdb = (tid >> 5) * 8;  // V: kv pair 2vp, 8 d

    // prefetch registers (T14: issued early, consumed next iteration)
    f32x4 pk0, pk1, pk2, pk3;   // K row kr, cols kc..kc+16
    f32x4 pv0, pv1, pv2, pv3;   // V rows 2vp,2vp+1, cols vdb..vdb+8

    auto ISSUE = [&](int k0) {
        const float* kp = K + ((size_t)(b * SDIM + k0 + kr)) * EMB + h * HD + kc;
        pk0 = *(const f32x4*)(kp + 0);
        pk1 = *(const f32x4*)(kp + 4);
        pk2 = *(const f32x4*)(kp + 8);
        pk3 = *(const f32x4*)(kp + 12);
        const float* v0p = V + ((size_t)(b * SDIM + k0 + 2 * vp)) * EMB + h * HD + vdb;
        pv0 = *(const f32x4*)(v0p);
        pv1 = *(const f32x4*)(v0p + 4);
        pv2 = *(const f32x4*)(v0p + EMB);
        pv3 = *(const f32x4*)(v0p + EMB + 4);
    };

    auto WRITE_STAGE = [&](int buf) {
        int rs = 8 * (kr & 7);
        u32x4 w0 = { cvt_pk(pk0[0],pk0[1]), cvt_pk(pk0[2],pk0[3]),
                     cvt_pk(pk1[0],pk1[1]), cvt_pk(pk1[2],pk1[3]) };
        u32x4 w1 = { cvt_pk(pk2[0],pk2[1]), cvt_pk(pk2[2],pk2[3]),
                     cvt_pk(pk3[0],pk3[1]), cvt_pk(pk3[2],pk3[3]) };
        *(u32x4*)&Kl[buf][kr * HD + ((kc + 0) ^ rs)] = w0;
        *(u32x4*)&Kl[buf][kr * HD + ((kc + 8) ^ rs)] = w1;
        unsigned* vt32 = (unsigned*)&Vt[buf][0];
#pragma unroll
        for (int i = 0; i < 4; ++i) {
            int d = vdb + i;
            vt32[d * 32 + (vp ^ (4 * (d & 7)))] = cvt_pk(pv0[i], pv2[i]);
        }
#pragma unroll
        for (int i = 0; i < 4; ++i) {
            int d = vdb + 4 + i;
            vt32[d * 32 + (vp ^ (4 * (d & 7)))] = cvt_pk(pv1[i], pv3[i]);
        }
    };

    // per-q-tile state
    bf16x8 qf0, qf1, qf2, qf3;
    float m2, l_run;
    f32x16 accO0, accO1;
    int qbase, q_g;

    auto LOAD_Q = [&]() {
        const float* qp = Q + ((size_t)(b * SDIM + q_g)) * EMB + h * HD + 8 * hi;
#pragma unroll
        for (int s = 0; s < 4; ++s) {
            f32x4 a = *(const f32x4*)(qp + 16 * s);
            f32x4 c = *(const f32x4*)(qp + 16 * s + 4);
            u32x4 w = { cvt_pk(a[0], a[1]), cvt_pk(a[2], a[3]),
                        cvt_pk(c[0], c[1]), cvt_pk(c[2], c[3]) };
            bf16x8 f = (bf16x8)w;
            if (s == 0) qf0 = f; else if (s == 1) qf1 = f;
            else if (s == 2) qf2 = f; else qf3 = f;
        }
    };
    auto INIT_STATE = [&]() {
        m2 = -1e30f; l_run = 0.f;
        accO0 = (f32x16){0.f,0.f,0.f,0.f,0.f,0.f,0.f,0.f,0.f,0.f,0.f,0.f,0.f,0.f,0.f,0.f};
        accO1 = accO0;
    };
    auto EPILOGUE = [&]() {
        float il = 1.f / l_run;
#pragma unroll
        for (int r = 0; r < 16; ++r) {
            float ir = __shfl(il, shbase + ((r & 3) + 8 * (r >> 2)), 64);
            int q = qbase + (r & 3) + 8 * (r >> 2) + 4 * hi;
            size_t base = ((size_t)(b * SDIM + q)) * EMB + h * HD;
            X[base + ln]      = (short)cvt_pk(accO0[r] * il * 0.f + accO0[r] * ir, 0.f);
            X[base + 32 + ln] = (short)cvt_pk(accO1[r] * ir, 0.f);
        }
    };

    auto COMPUTE = [&](int buf, int k0) {
        float p0[16], p1[16];
#pragma unroll
        for (int t = 0; t < 2; ++t) {
            f32x16 acc = (f32x16){0.f,0.f,0.f,0.f,0.f,0.f,0.f,0.f,
                                  0.f,0.f,0.f,0.f,0.f,0.f,0.f,0.f};
            __builtin_amdgcn_s_setprio(1);
#pragma unroll
            for (int s = 0; s < 4; ++s) {
                bf16x8 kf = *(bf16x8*)&Kl[buf][(32*t + ln) * HD + ((16*s + 8*hi) ^ swz)];
                bf16x8 qs = (s == 0) ? qf0 : (s == 1) ? qf1 : (s == 2) ? qf2 : qf3;
                acc = __builtin_amdgcn_mfma_f32_32x32x16_bf16(kf, qs, acc, 0, 0, 0);
            }
            __builtin_amdgcn_s_setprio(0);
            float* pt = t ? p1 : p0;
            if (k0 + 32*t + 31 > qbase) {
#pragma unroll
                for (int r = 0; r < 16; ++r) {
                    int kv = k0 + 32*t + (r & 3) + 8*(r >> 2) + 4*hi;
                    pt[r] = (kv > q_g) ? -INFINITY : acc[r] * SC;
                }
            } else {
#pragma unroll
                for (int r = 0; r < 16; ++r) pt[r] = acc[r] * SC;
            }
        }

        float mt = fmaxf(p0[0], p1[0]);
#pragma unroll
        for (int r = 1; r < 16; ++r) mt = fmaxf(mt, fmaxf(p0[r], p1[r]));
        mt = fmaxf(mt, __shfl_xor(mt, 32, 64));

        if (!__all(mt <= m2 + THR)) {            // T13 defer-max
            float m_new = fmaxf(m2, mt);
            float fac = __builtin_amdgcn_exp2f(m2 - m_new);
            m2 = m_new;
            l_run *= fac;
#pragma unroll
            for (int r = 0; r < 16; ++r) {
                float fr = __shfl(fac, shbase + ((r & 3) + 8*(r >> 2)), 64);
                accO0[r] *= fr;
                accO1[r] *= fr;
            }
        }
        float psum = 0.f;
#pragma unroll
        for (int r = 0; r < 16; ++r) { p0[r] = __builtin_amdgcn_exp2f(p0[r] - m2); psum += p0[r]; }
#pragma unroll
        for (int r = 0; r < 16; ++r) { p1[r] = __builtin_amdgcn_exp2f(p1[r] - m2); psum += p1[r]; }
        psum += __shfl_xor(psum, 32, 64);
        l_run += psum;

        // T12 repack P -> A-frags + PV
#pragma unroll
        for (int s = 0; s < 4; ++s) {
            const float* pt = (s >= 2) ? p1 : p0;
            const int u8 = (s & 1) * 8;
            unsigned w0 = cvt_pk(pt[u8 + 0], pt[u8 + 1]);
            unsigned w2 = cvt_pk(pt[u8 + 4], pt[u8 + 5]);
            pl32swap(w0, w2);
            unsigned w1 = cvt_pk(pt[u8 + 2], pt[u8 + 3]);
            unsigned w3 = cvt_pk(pt[u8 + 6], pt[u8 + 7]);
            pl32swap(w1, w3);
            u32x4 pw = { w0, w1, w2, w3 };
            bf16x8 pa = (bf16x8)pw;
            bf16x8 v0f = *(bf16x8*)&Vt[buf][(ln)      * KVB + ((16*s + 8*hi) ^ swz)];
            bf16x8 v1f = *(bf16x8*)&Vt[buf][(32 + ln) * KVB + ((16*s + 8*hi) ^ swz)];
            __builtin_amdgcn_s_setprio(1);
            accO0 = __builtin_amdgcn_mfma_f32_32x32x16_bf16(pa, v0f, accO0, 0, 0, 0);
            accO1 = __builtin_amdgcn_mfma_f32_32x32x16_bf16(pa, v1f, accO1, 0, 0, 0);
            __builtin_amdgcn_s_setprio(0);
        }
    };

    // ---- q-tile pair: heavy (31-pair) first, then light (pair) ----
    const int qt0 = NQT - 1 - pair;
    const int nt0 = 2 * qt0 + 2;
    const int ntot = 66;                 // nt0 + (2*pair+2), constant

    qbase = qt0 * QBLK + wave * 32;
    q_g = qbase + ln;
    LOAD_Q();
    INIT_STATE();
    ISSUE(0);

    for (int g = 0; g < ntot; ++g) {
        if (g == nt0) {                  // segment switch: light tile
            EPILOGUE();
            qbase = pair * QBLK + wave * 32;
            q_g = qbase + ln;
            LOAD_Q();
            INIT_STATE();
        }
        int buf = g & 1;
        WRITE_STAGE(buf);                // implicit vmcnt on prefetched regs
        int gn = g + 1;
        if (gn < ntot) {                 // T14: issue next tile's loads now
            int k0n = (gn < nt0 ? gn : gn - nt0) * KVB;
            ISSUE(k0n);
        }
        __builtin_amdgcn_sched_barrier(0);
        __syncthreads();                 // single barrier (double-buffered)
        int k0 = (g < nt0 ? g : g - nt0) * KVB;
        if (k0 <= qbase + 31) COMPUTE(buf, k0);
    }
    EPILOGUE();
}

// ---------------------------------------------------------------------------
// Output projection: out[i][j] = sum_e X[i][e] * Wo[j][e] + bo[j]
// ---------------------------------------------------------------------------
__global__ __launch_bounds__(256, 2) void proj_gemm(
    const short* __restrict__ X, const float* __restrict__ Wo,
    const float* __restrict__ bo, float* __restrict__ out)
{
    __shared__ short Alds[64][40];
    __shared__ short Blds[64][40];

    int bj = blockIdx.x & 7;
    int bi = blockIdx.x >> 3;
    int i0 = bi * 64, j0 = bj * 64;

    int tid  = threadIdx.x;
    int wave = tid >> 6, lane = tid & 63;
    int g = lane >> 4, ln = lane & 15;
    int srow = tid >> 2, scol = (tid & 3) * 8;

    f32x4 acc[4];
#pragma unroll
    for (int i = 0; i < 4; ++i) acc[i] = (f32x4){0.f, 0.f, 0.f, 0.f};

    for (int e0 = 0; e0 < EMB; e0 += 32) {
        bf16x8 xa = *(const bf16x8*)&X[(size_t)(i0 + srow) * EMB + e0 + scol];
        *(bf16x8*)&Alds[srow][scol] = xa;

        const float* wp = Wo + (size_t)(j0 + srow) * EMB + e0 + scol;
        f32x4 a = *(const f32x4*)wp;
        f32x4 c = *(const f32x4*)(wp + 4);
        u32x4 w = { cvt_pk(a[0], a[1]), cvt_pk(a[2], a[3]),
                    cvt_pk(c[0], c[1]), cvt_pk(c[2], c[3]) };
        *(u32x4*)&Blds[srow][scol] = w;
        __syncthreads();

        bf16x8 af = *(bf16x8*)&Alds[wave * 16 + ln][g * 8];
#pragma unroll
        for (int nt = 0; nt < 4; ++nt) {
            bf16x8 bf = *(bf16x8*)&Blds[nt * 16 + ln][g * 8];
            acc[nt] = __builtin_amdgcn_mfma_f32_16x16x32_bf16(af, bf, acc[nt], 0, 0, 0);
        }
        __syncthreads();
    }

#pragma unroll
    for (int nt = 0; nt < 4; ++nt)
#pragma unroll
        for (int r = 0; r < 4; ++r) {
            int row = i0 + wave * 16 + g * 4 + r;
            int col = j0 + nt * 16 + ln;
            out[(size_t)row * EMB + col] = acc[nt][r] + bo[col];
        }
}

extern "C" void kernel_launch(void* const* d_in, const int* in_sizes, int n_in,
                              void* d_out, int out_size, void* d_ws, size_t ws_size,
                              hipStream_t stream) {
    const float* Q  = (const float*)d_in[0];
    const float* K  = (const float*)d_in[1];
    const float* V  = (const float*)d_in[2];
    const float* Wo = (const float*)d_in[3];
    const float* bo = (const float*)d_in[4];
    short* X   = (short*)d_ws;                 // bf16 attn output [B*S][EMB] = 16 MB
    float* out = (float*)d_out;

    attn_fwd<<<dim3(NB * NH * NPAIR), 256, 0, stream>>>(Q, K, V, X);
    proj_gemm<<<dim3((NB * SDIM / 64) * (EMB / 64)), 256, 0, stream>>>(X, Wo, bo, out);
}

// Round 4
// 97.832 us; speedup vs baseline: 3.6445x; 1.2944x over previous
//
#include <hip/hip_runtime.h>
#include <hip/hip_bf16.h>
#include <math.h>

#define SDIM 4096
#define EMB 512
#define NH 8
#define HD 64
#define QBLK 128            // per q-tile: 4 waves x 32 q-rows (per team)
#define KVB 64
#define NB 2
#define NQT (SDIM / QBLK)   // 32
#define NPAIR (NQT / 2)     // 16

typedef __attribute__((ext_vector_type(4)))  float f32x4;
typedef __attribute__((ext_vector_type(16))) float f32x16;
typedef __attribute__((ext_vector_type(8)))  short bf16x8;
typedef __attribute__((ext_vector_type(4)))  unsigned u32x4;

#define SCQ 0.18033688011112042f   // log2(e) / sqrt(64), folded into Q
#define THR 8.0f                   // defer-max threshold, log2 units

__device__ __forceinline__ unsigned cvt_pk(float lo, float hi) {
    unsigned r;
    asm("v_cvt_pk_bf16_f32 %0, %1, %2" : "=v"(r) : "v"(lo), "v"(hi));
    return r;
}
__device__ __forceinline__ void pl32swap(unsigned &a, unsigned &b) {
    asm("v_permlane32_swap_b32 %0, %1" : "+v"(a), "+v"(b));
}

// ---------------------------------------------------------------------------
// Flash attention (causal). Block = (b,h) x q-tile PAIR (31-p, p): 66 KV-tile
// units per block, perfectly balanced. 512 threads = 2 teams x 4 waves.
// Teams split each segment's KV tiles (even/odd), private (m,l,O) + private
// double-buffered LDS; flash-combine merge at segment end via LDS overlay.
// 32x32x16 MFMA, swapped QK^T (q lane-local), T12 cvt_pk/permlane repack,
// T13 defer-max, T14 async-STAGE split, T2 XOR-swizzle, T5 setprio.
// ---------------------------------------------------------------------------
__global__ __launch_bounds__(512) void attn_fwd(
    const float* __restrict__ Q, const float* __restrict__ K,
    const float* __restrict__ V, short* __restrict__ X)
{
    __shared__ short smem[32768];       // 64KB: [team][buf][K(4096) | V(4096)]
    __shared__ float mlb[4][32][2];     // merge: per wave-pair m,l

    int bh   = blockIdx.x & 15;         // bh-major -> same bh shares an XCD L2
    int pair = blockIdx.x >> 4;
    int b = bh / NH, h = bh % NH;

    int tid  = threadIdx.x;
    int wave = tid >> 6, lane = tid & 63;
    int team = wave >> 2, w = wave & 3;
    int ln = lane & 31, hi = lane >> 5;
    int swz = 8 * (ln & 7);
    int shbase = 36 * hi;               // (lane&32) + 4*hi

    // per-team staging maps (256 threads per team)
    int ttid = tid & 255;
    const int kr = ttid >> 2, kc = (ttid & 3) * 16;   // K: row kr, 16 d
    const int vp = ttid & 31, vdb = (ttid >> 5) * 8;  // V: kv pair 2vp, 8 d

    // prefetch registers (T14)
    f32x4 pk0, pk1, pk2, pk3, pv0, pv1, pv2, pv3;

    auto ISSUE = [&](int k0) {
        const float* kp = K + ((size_t)(b * SDIM + k0 + kr)) * EMB + h * HD + kc;
        pk0 = *(const f32x4*)(kp + 0);
        pk1 = *(const f32x4*)(kp + 4);
        pk2 = *(const f32x4*)(kp + 8);
        pk3 = *(const f32x4*)(kp + 12);
        const float* v0p = V + ((size_t)(b * SDIM + k0 + 2 * vp)) * EMB + h * HD + vdb;
        pv0 = *(const f32x4*)(v0p);
        pv1 = *(const f32x4*)(v0p + 4);
        pv2 = *(const f32x4*)(v0p + EMB);
        pv3 = *(const f32x4*)(v0p + EMB + 4);
    };

    auto WRITE_STAGE = [&](int buf) {
        short* Klp = &smem[(team * 2 + buf) * 8192];
        short* Vtp = Klp + 4096;
        int rs = 8 * (kr & 7);
        u32x4 w0 = { cvt_pk(pk0[0],pk0[1]), cvt_pk(pk0[2],pk0[3]),
                     cvt_pk(pk1[0],pk1[1]), cvt_pk(pk1[2],pk1[3]) };
        u32x4 w1 = { cvt_pk(pk2[0],pk2[1]), cvt_pk(pk2[2],pk2[3]),
                     cvt_pk(pk3[0],pk3[1]), cvt_pk(pk3[2],pk3[3]) };
        *(u32x4*)&Klp[kr * HD + ((kc + 0) ^ rs)] = w0;
        *(u32x4*)&Klp[kr * HD + ((kc + 8) ^ rs)] = w1;
        unsigned* vt32 = (unsigned*)Vtp;
#pragma unroll
        for (int i = 0; i < 4; ++i) {
            int d = vdb + i;
            vt32[d * 32 + (vp ^ (4 * (d & 7)))] = cvt_pk(pv0[i], pv2[i]);
        }
#pragma unroll
        for (int i = 0; i < 4; ++i) {
            int d = vdb + 4 + i;
            vt32[d * 32 + (vp ^ (4 * (d & 7)))] = cvt_pk(pv1[i], pv3[i]);
        }
    };

    // per-segment state
    bf16x8 qf0, qf1, qf2, qf3;
    float m2, l_run;
    f32x16 accO0, accO1;
    int qbase, q_g;

    auto LOAD_Q = [&]() {   // pre-scaled by SCQ (log2-domain scores from MFMA)
        const float* qp = Q + ((size_t)(b * SDIM + q_g)) * EMB + h * HD + 8 * hi;
#pragma unroll
        for (int s = 0; s < 4; ++s) {
            f32x4 a = *(const f32x4*)(qp + 16 * s) * SCQ;
            f32x4 c = *(const f32x4*)(qp + 16 * s + 4) * SCQ;
            u32x4 wq = { cvt_pk(a[0], a[1]), cvt_pk(a[2], a[3]),
                         cvt_pk(c[0], c[1]), cvt_pk(c[2], c[3]) };
            bf16x8 f = (bf16x8)wq;
            if (s == 0) qf0 = f; else if (s == 1) qf1 = f;
            else if (s == 2) qf2 = f; else qf3 = f;
        }
    };

    auto COMPUTE = [&](int buf, int k0) {
        short* Klp = &smem[(team * 2 + buf) * 8192];
        short* Vtp = Klp + 4096;
        float p0[16], p1[16];
#pragma unroll
        for (int t = 0; t < 2; ++t) {
            f32x16 acc = (f32x16){0.f,0.f,0.f,0.f,0.f,0.f,0.f,0.f,
                                  0.f,0.f,0.f,0.f,0.f,0.f,0.f,0.f};
            __builtin_amdgcn_s_setprio(1);
#pragma unroll
            for (int s = 0; s < 4; ++s) {
                bf16x8 kf = *(bf16x8*)&Klp[(32*t + ln) * HD + ((16*s + 8*hi) ^ swz)];
                bf16x8 qs = (s == 0) ? qf0 : (s == 1) ? qf1 : (s == 2) ? qf2 : qf3;
                acc = __builtin_amdgcn_mfma_f32_32x32x16_bf16(kf, qs, acc, 0, 0, 0);
            }
            __builtin_amdgcn_s_setprio(0);
            float* pt = t ? p1 : p0;
            if (k0 + 32*t + 31 > qbase) {          // diagonal-crossing: mask
#pragma unroll
                for (int r = 0; r < 16; ++r) {
                    int kv = k0 + 32*t + (r & 3) + 8*(r >> 2) + 4*hi;
                    pt[r] = (kv > q_g) ? -INFINITY : acc[r];
                }
            } else {
#pragma unroll
                for (int r = 0; r < 16; ++r) pt[r] = acc[r];
            }
        }

        // tree max (depth ~5)
        float mx[16];
#pragma unroll
        for (int r = 0; r < 16; ++r) mx[r] = fmaxf(p0[r], p1[r]);
#pragma unroll
        for (int r = 0; r < 8; ++r) mx[r] = fmaxf(mx[r], mx[r + 8]);
#pragma unroll
        for (int r = 0; r < 4; ++r) mx[r] = fmaxf(mx[r], mx[r + 4]);
        float mt = fmaxf(fmaxf(mx[0], mx[1]), fmaxf(mx[2], mx[3]));
        mt = fmaxf(mt, __shfl_xor(mt, 32, 64));

        if (!__all(mt <= m2 + THR)) {              // T13 defer-max
            float m_new = fmaxf(m2, mt);
            float fac = __builtin_amdgcn_exp2f(m2 - m_new);
            m2 = m_new;
            l_run *= fac;
#pragma unroll
            for (int r = 0; r < 16; ++r) {
                float fr = __shfl(fac, shbase + ((r & 3) + 8*(r >> 2)), 64);
                accO0[r] *= fr;
                accO1[r] *= fr;
            }
        }
        // exp2 + tree sum
        float sm[16];
#pragma unroll
        for (int r = 0; r < 16; ++r) {
            p0[r] = __builtin_amdgcn_exp2f(p0[r] - m2);
            p1[r] = __builtin_amdgcn_exp2f(p1[r] - m2);
            sm[r] = p0[r] + p1[r];
        }
#pragma unroll
        for (int r = 0; r < 8; ++r) sm[r] += sm[r + 8];
#pragma unroll
        for (int r = 0; r < 4; ++r) sm[r] += sm[r + 4];
        float psum = (sm[0] + sm[1]) + (sm[2] + sm[3]);
        psum += __shfl_xor(psum, 32, 64);
        l_run += psum;

        // T12 repack P -> A-frags + PV
#pragma unroll
        for (int s = 0; s < 4; ++s) {
            const float* pt = (s >= 2) ? p1 : p0;
            const int u8 = (s & 1) * 8;
            unsigned w0 = cvt_pk(pt[u8 + 0], pt[u8 + 1]);
            unsigned w2 = cvt_pk(pt[u8 + 4], pt[u8 + 5]);
            pl32swap(w0, w2);
            unsigned w1 = cvt_pk(pt[u8 + 2], pt[u8 + 3]);
            unsigned w3 = cvt_pk(pt[u8 + 6], pt[u8 + 7]);
            pl32swap(w1, w3);
            u32x4 pw = { w0, w1, w2, w3 };
            bf16x8 pa = (bf16x8)pw;
            bf16x8 v0f = *(bf16x8*)&Vtp[(ln)      * KVB + ((16*s + 8*hi) ^ swz)];
            bf16x8 v1f = *(bf16x8*)&Vtp[(32 + ln) * KVB + ((16*s + 8*hi) ^ swz)];
            __builtin_amdgcn_s_setprio(1);
            accO0 = __builtin_amdgcn_mfma_f32_32x32x16_bf16(pa, v0f, accO0, 0, 0, 0);
            accO1 = __builtin_amdgcn_mfma_f32_32x32x16_bf16(pa, v1f, accO1, 0, 0, 0);
            __builtin_amdgcn_s_setprio(0);
        }
    };

    // flash-combine merge (team1 -> LDS, team0 merges + writes X)
    auto FINISH = [&]() {
        __syncthreads();
        f32x4* O4 = (f32x4*)&smem[16384];   // 32KB overlay on team1 KV region
        if (team == 1) {
            if (hi == 0) { mlb[w][ln][0] = m2; mlb[w][ln][1] = l_run; }
#pragma unroll
            for (int rq = 0; rq < 4; ++rq)
                O4[(w * 8 + rq) * 64 + lane] =
                    (f32x4){accO0[4*rq], accO0[4*rq+1], accO0[4*rq+2], accO0[4*rq+3]};
#pragma unroll
            for (int rq = 0; rq < 4; ++rq)
                O4[(w * 8 + 4 + rq) * 64 + lane] =
                    (f32x4){accO1[4*rq], accO1[4*rq+1], accO1[4*rq+2], accO1[4*rq+3]};
        }
        __syncthreads();
        if (team == 0) {
            float mB = mlb[w][ln][0], lB = mlb[w][ln][1];
            float m  = fmaxf(m2, mB);
            float aS = __builtin_amdgcn_exp2f(m2 - m);
            float bS = __builtin_amdgcn_exp2f(mB - m);
            float il = 1.f / (l_run * aS + lB * bS);
            float fa = aS * il, fb = bS * il;
            f32x4 ob[8];
#pragma unroll
            for (int rq = 0; rq < 8; ++rq) ob[rq] = O4[(w * 8 + rq) * 64 + lane];
#pragma unroll
            for (int r = 0; r < 16; ++r) {
                int crow = (r & 3) + 8 * (r >> 2);
                float faR = __shfl(fa, shbase + crow, 64);
                float fbR = __shfl(fb, shbase + crow, 64);
                float o0 = accO0[r] * faR + ob[r >> 2][r & 3] * fbR;
                float o1 = accO1[r] * faR + ob[4 + (r >> 2)][r & 3] * fbR;
                int q = qbase + crow + 4 * hi;
                size_t base = ((size_t)(b * SDIM + q)) * EMB + h * HD;
                X[base + ln]      = (short)cvt_pk(o0, 0.f);
                X[base + 32 + ln] = (short)cvt_pk(o1, 0.f);
            }
        }
        __syncthreads();
    };

    auto RUN_SEG = [&](int qt) {
        qbase = qt * QBLK + w * 32;
        q_g = qbase + ln;
        LOAD_Q();
        m2 = -1e30f; l_run = 0.f;
        accO0 = (f32x16){0.f,0.f,0.f,0.f,0.f,0.f,0.f,0.f,0.f,0.f,0.f,0.f,0.f,0.f,0.f,0.f};
        accO1 = accO0;
        const int nt  = 2 * qt + 2;        // always even
        const int cnt = nt >> 1;           // tiles per team
        ISSUE(team * KVB);
        for (int i = 0; i < cnt; ++i) {
            int buf = i & 1;
            WRITE_STAGE(buf);
            int tn = 2 * (i + 1) + team;   // T14: next tile's loads in flight
            if (tn < nt) ISSUE(tn * KVB);
            __builtin_amdgcn_sched_barrier(0);
            __syncthreads();
            int k0 = (2 * i + team) * KVB;
            if (k0 <= qbase + 31) COMPUTE(buf, k0);
        }
        FINISH();
    };

    RUN_SEG(NQT - 1 - pair);   // heavy segment
    RUN_SEG(pair);             // light segment
}

// ---------------------------------------------------------------------------
// Output projection: out[i][j] = sum_e X[i][e] * Wo[j][e] + bo[j]
// ---------------------------------------------------------------------------
__global__ __launch_bounds__(256, 2) void proj_gemm(
    const short* __restrict__ X, const float* __restrict__ Wo,
    const float* __restrict__ bo, float* __restrict__ out)
{
    __shared__ short Alds[64][40];
    __shared__ short Blds[64][40];

    int bj = blockIdx.x & 7;
    int bi = blockIdx.x >> 3;
    int i0 = bi * 64, j0 = bj * 64;

    int tid  = threadIdx.x;
    int wave = tid >> 6, lane = tid & 63;
    int g = lane >> 4, ln = lane & 15;
    int srow = tid >> 2, scol = (tid & 3) * 8;

    f32x4 acc[4];
#pragma unroll
    for (int i = 0; i < 4; ++i) acc[i] = (f32x4){0.f, 0.f, 0.f, 0.f};

    for (int e0 = 0; e0 < EMB; e0 += 32) {
        bf16x8 xa = *(const bf16x8*)&X[(size_t)(i0 + srow) * EMB + e0 + scol];
        *(bf16x8*)&Alds[srow][scol] = xa;

        const float* wp = Wo + (size_t)(j0 + srow) * EMB + e0 + scol;
        f32x4 a = *(const f32x4*)wp;
        f32x4 c = *(const f32x4*)(wp + 4);
        u32x4 w = { cvt_pk(a[0], a[1]), cvt_pk(a[2], a[3]),
                    cvt_pk(c[0], c[1]), cvt_pk(c[2], c[3]) };
        *(u32x4*)&Blds[srow][scol] = w;
        __syncthreads();

        bf16x8 af = *(bf16x8*)&Alds[wave * 16 + ln][g * 8];
#pragma unroll
        for (int nt = 0; nt < 4; ++nt) {
            bf16x8 bf = *(bf16x8*)&Blds[nt * 16 + ln][g * 8];
            acc[nt] = __builtin_amdgcn_mfma_f32_16x16x32_bf16(af, bf, acc[nt], 0, 0, 0);
        }
        __syncthreads();
    }

#pragma unroll
    for (int nt = 0; nt < 4; ++nt)
#pragma unroll
        for (int r = 0; r < 4; ++r) {
            int row = i0 + wave * 16 + g * 4 + r;
            int col = j0 + nt * 16 + ln;
            out[(size_t)row * EMB + col] = acc[nt][r] + bo[col];
        }
}

extern "C" void kernel_launch(void* const* d_in, const int* in_sizes, int n_in,
                              void* d_out, int out_size, void* d_ws, size_t ws_size,
                              hipStream_t stream) {
    const float* Q  = (const float*)d_in[0];
    const float* K  = (const float*)d_in[1];
    const float* V  = (const float*)d_in[2];
    const float* Wo = (const float*)d_in[3];
    const float* bo = (const float*)d_in[4];
    short* X   = (short*)d_ws;                 // bf16 attn output [B*S][EMB] = 16 MB
    float* out = (float*)d_out;

    attn_fwd<<<dim3(NB * NH * NPAIR), 512, 0, stream>>>(Q, K, V, X);
    proj_gemm<<<dim3((NB * SDIM / 64) * (EMB / 64)), 256, 0, stream>>>(X, Wo, bo, out);
}